// Round 10
// baseline (1120.009 us; speedup 1.0000x reference)
//
#include <hip/hip_runtime.h>
#include <math.h>

#define NTOK 32768
typedef unsigned short ushort_t;

// d_out offsets (in floats)
#define OFF_CENT 0
#define OFF_SE   131072
#define OFF_WC   16908288
#define OFF_SC   16973824
#define OFF_OT   17039360
#define OFF_CT   17072128
#define OFF_OI   17072640
#define OFF_CI   17105408

typedef __attribute__((ext_vector_type(8))) short short8v;
typedef __attribute__((ext_vector_type(4))) float f32x4;
typedef __attribute__((ext_vector_type(16))) float f32x16;

// plane-major block constants (ushort units):
// [rowblk 256][ktile 32][plane 4][row 256][elem 8]; RBLK = 32*4*256*8
#define PLANE 2048
#define KTBLK 8192
#define RBLK  262144

__device__ __forceinline__ float dot4(float4 a, float4 b){
    return a.x*b.x + a.y*b.y + a.z*b.z + a.w*b.w;
}

// RNE float -> bf16 bits
__device__ __forceinline__ ushort_t f2bf(float x){
    unsigned int u = __float_as_uint(x);
    unsigned int r = (u + 0x7fffu + ((u >> 16) & 1u)) >> 16;
    return (ushort_t)r;
}
__device__ __forceinline__ float bf2f(ushort_t h){
    return __uint_as_float(((unsigned int)h) << 16);
}

__device__ __forceinline__ void gload16(const void* g, void* l){
    __builtin_amdgcn_global_load_lds(
        (const __attribute__((address_space(1))) void*)g,
        (__attribute__((address_space(3))) void*)l,
        16, 0, 0);
}

// split 8 fp32 -> 8 bf16 hi + 8 bf16 lo
__device__ __forceinline__ void cvt8(float4 a, float4 b, short8v& h, short8v& l){
    float x[8] = {a.x, a.y, a.z, a.w, b.x, b.y, b.z, b.w};
    #pragma unroll
    for (int i = 0; i < 8; ++i) {
        ushort_t hh = f2bf(x[i]);
        h[i] = (short)hh;
        l[i] = (short)f2bf(x[i] - bf2f(hh));
    }
}

// ---------------- centroids: tanh + c2 + hi/lo split ----------------
__global__ __launch_bounds__(64) void k_cent(const float* __restrict__ raw,
                                             float* __restrict__ out,
                                             float* __restrict__ c2,
                                             ushort_t* __restrict__ ch,
                                             ushort_t* __restrict__ cl)
{
    int c = blockIdx.x, l = threadIdx.x;
    float4 v = *(const float4*)(raw + (size_t)c*256 + l*4);
    float4 t;
    t.x = tanhf(v.x); t.y = tanhf(v.y); t.z = tanhf(v.z); t.w = tanhf(v.w);
    *(float4*)(out + OFF_CENT + (size_t)c*256 + l*4) = t;
    ushort4 h = make_ushort4(f2bf(t.x), f2bf(t.y), f2bf(t.z), f2bf(t.w));
    ushort4 lo = make_ushort4(f2bf(t.x - bf2f(h.x)), f2bf(t.y - bf2f(h.y)),
                              f2bf(t.z - bf2f(h.z)), f2bf(t.w - bf2f(h.w)));
    *(ushort4*)(ch + (size_t)c*256 + l*4) = h;
    *(ushort4*)(cl + (size_t)c*256 + l*4) = lo;
    float s = dot4(t, t);
    #pragma unroll
    for (int off = 32; off > 0; off >>= 1) s += __shfl_down(s, off);
    if (l == 0) c2[c] = s;
}

// ---------------- weight transpose + split: plane-major dest (W1,W2) ----------------
__device__ __forceinline__ void wsplit_plane(const float* __restrict__ W,
                                             ushort_t* __restrict__ Wt_hi,
                                             ushort_t* __restrict__ Wt_lo,
                                             int N, int bx, int by)
{
    __shared__ float t[32][33];
    int k0 = by*32, n0 = bx*32;
    int tx = threadIdx.x & 31, ty = threadIdx.x >> 5;
    #pragma unroll
    for (int r = 0; r < 4; ++r)
        t[ty + r*8][tx] = W[(size_t)(k0 + ty + r*8)*N + n0 + tx];
    __syncthreads();
    // element (k = k0+tx, n = n0+nl): plane-major dest
    const int kt = k0 >> 5;
    const int s  = tx >> 3, e = tx & 7;
    #pragma unroll
    for (int r = 0; r < 4; ++r) {
        int nl = ty + r*8;
        int n = n0 + nl;
        float x = t[tx][nl];
        ushort_t h = f2bf(x);
        size_t dst = (size_t)(n >> 8)*RBLK + (size_t)kt*KTBLK + s*PLANE + (n & 255)*8 + e;
        Wt_hi[dst] = h;
        Wt_lo[dst] = f2bf(x - bf2f(h));
    }
}

// ---------------- W3: plain row-major [N][K] (consumed by 128^2 L3 kernel) ----------------
__device__ __forceinline__ void wsplit_plain(const float* __restrict__ W,
                                             ushort_t* __restrict__ Wt_hi,
                                             ushort_t* __restrict__ Wt_lo,
                                             int K, int N, int bx, int by)
{
    __shared__ float t[32][33];
    int k0 = by*32, n0 = bx*32;
    int tx = threadIdx.x & 31, ty = threadIdx.x >> 5;
    #pragma unroll
    for (int r = 0; r < 4; ++r)
        t[ty + r*8][tx] = W[(size_t)(k0 + ty + r*8)*N + n0 + tx];
    __syncthreads();
    #pragma unroll
    for (int r = 0; r < 4; ++r) {
        int n = ty + r*8;
        float x = t[tx][n];
        ushort_t h = f2bf(x);
        Wt_hi[(size_t)(n0+n)*K + k0 + tx] = h;
        Wt_lo[(size_t)(n0+n)*K + k0 + tx] = f2bf(x - bf2f(h));
    }
}

// ---------------- combined prep: weight splits + word_class ----------------
__global__ __launch_bounds__(256) void k_prep(
    const float* __restrict__ W1t, const float* __restrict__ W2t, const float* __restrict__ W3t,
    const float* __restrict__ W1i, const float* __restrict__ W2i, const float* __restrict__ W3i,
    ushort_t* __restrict__ wreg, float* __restrict__ out)
{
    const size_t WM = 4*1048576 + 2*262144;
    int b = blockIdx.x;
    if (b >= 4608) {
        int g = (b - 4608)*256 + threadIdx.x;
        float v = (g*4 < NTOK) ? 0.f : 1.f;
        ((float4*)(out + OFF_WC))[g] = make_float4(v, v, v, v);
        return;
    }
    int m = b / 2304;
    int r = b % 2304;
    ushort_t* base = wreg + (size_t)m*WM;
    const float* Ws[3][2] = {{W1t, W1i}, {W2t, W2i}, {W3t, W3i}};
    if (r < 1024) {
        wsplit_plane(Ws[0][m], base, base + 1048576, 1024, r % 32, r / 32);
    } else if (r < 2048) {
        int r2 = r - 1024;
        wsplit_plane(Ws[1][m], base + 2*1048576, base + 3*1048576, 1024, r2 % 32, r2 / 32);
    } else {
        int r3 = r - 2048;
        wsplit_plain(Ws[2][m], base + 4*1048576, base + 4*1048576 + 262144, 1024, 256, r3 % 8, r3 / 8);
    }
}

// shared MFMA body: 48 x mfma_f32_32x32x16_bf16 per K-tile per wave
#define MM32(A8, B8, C16) __builtin_amdgcn_mfma_f32_32x32x16_bf16(A8, B8, C16, 0, 0, 0)

// fragment reads from plane-major LDS regions (Ah 0 / Al 8192 / Bh 16384 / Bl 24576 ushorts)
#define RAP(P, hl, kk, i) (*(const short8v*)((P) + (hl)*8192u + (kk)*4096u + (unsigned)(i)*256u))
#define RBP(P, hl, kk, j) (*(const short8v*)((P) + 16384u + (hl)*8192u + (kk)*4096u + (unsigned)(j)*256u))

#define MFMA_TILE(PA, PB) { \
    short8v b000 = RBP(PB,0,0,0), b001 = RBP(PB,1,0,0); \
    short8v b010 = RBP(PB,0,1,0), b011 = RBP(PB,1,1,0); \
    short8v b100 = RBP(PB,0,0,1), b101 = RBP(PB,1,0,1); \
    short8v b110 = RBP(PB,0,1,1), b111 = RBP(PB,1,1,1); \
    __builtin_amdgcn_s_setprio(1); \
    _Pragma("unroll") \
    for (int i = 0; i < 4; ++i) { \
        short8v ah0 = RAP(PA,0,0,i), al0 = RAP(PA,1,0,i); \
        short8v ah1 = RAP(PA,0,1,i), al1 = RAP(PA,1,1,i); \
        acc[i][0] = MM32(ah0, b000, acc[i][0]); \
        acc[i][1] = MM32(ah0, b100, acc[i][1]); \
        acc[i][0] = MM32(ah0, b001, acc[i][0]); \
        acc[i][1] = MM32(ah0, b101, acc[i][1]); \
        acc[i][0] = MM32(al0, b000, acc[i][0]); \
        acc[i][1] = MM32(al0, b100, acc[i][1]); \
        acc[i][0] = MM32(ah1, b010, acc[i][0]); \
        acc[i][1] = MM32(ah1, b110, acc[i][1]); \
        acc[i][0] = MM32(ah1, b011, acc[i][0]); \
        acc[i][1] = MM32(ah1, b111, acc[i][1]); \
        acc[i][0] = MM32(al1, b010, acc[i][0]); \
        acc[i][1] = MM32(al1, b110, acc[i][1]); \
    } \
    __builtin_amdgcn_s_setprio(0); \
}

// ================= layer-1: fused fp32-A split + 256x256 GEMM + tanh (32x32 MFMA) ======
// A fp32 row-major; staged via regs -> plane-major ds_write. B plane-major via gload.
// Output H written PLANE-MAJOR (consumed by k_gemm_l2).
__global__ __launch_bounds__(512, 2) void k_gemm_l1(
    const float* __restrict__ Af, const ushort_t* __restrict__ Btp,
    ushort_t* __restrict__ C_hi, ushort_t* __restrict__ C_lo,
    unsigned bDelta)
{
    __shared__ ushort_t lds[65536];   // 2 bufs x { Ah Al Bh Bl } each 8192 ushorts (plane-major)

    const int tid  = threadIdx.x;
    const int wave = tid >> 6, lane = tid & 63;
    const int wr = wave >> 2, wc = wave & 3;
    const int l31 = lane & 31, lk = lane >> 5;

    int nwg = gridDim.x;
    int id = blockIdx.x;
    if (!(nwg & 7)) { int cpx = nwg >> 3; id = (id & 7)*cpx + (id >> 3); }
    const int n0 = (id & 3) * 256;          // nx = 4 (N=1024)
    const int m0 = (id >> 2) * 256;

    // A reg-stage coords: thread covers (rows sr, sr+128) x slot q (8 k-elems)
    const int q  = tid & 3;
    const int sr = tid >> 2;
    const float* fA0 = Af + (size_t)(m0 + sr) * 1024 + q*8;
    const float* fA1 = fA0 + 131072;
    const unsigned aw0 = (unsigned)q*PLANE + (unsigned)sr*8u;   // plane-major ds_write dest
    const unsigned aw1 = aw0 + 1024u;                           // +128 rows

    // B staging: linear plane-major copy; per-lane source
    const ushort_t* pB0 = Btp + (size_t)(n0 >> 8)*RBLK + wave*512 + lane*8;
    const ushort_t* pB0l = pB0 + bDelta;
    const unsigned ldsB0 = 16384u + (unsigned)wave*512u;

    // fragment read bases
    const unsigned fbu = (unsigned)lk*PLANE + (unsigned)l31*8u;
    const ushort_t* pA = lds + fbu + (unsigned)wr*1024u;
    const ushort_t* pB = lds + fbu + (unsigned)wc*512u;
    const ushort_t* pA1b = pA + 32768u;
    const ushort_t* pB1b = pB + 32768u;

    f32x16 acc[4][2] = {};

#define STGB1(KT, WB) { \
    unsigned wb_ = (unsigned)(WB) * 32768u; \
    unsigned ko = (unsigned)(KT) * 256u; \
    gload16(pB0  + ko,        lds + wb_ + ldsB0); \
    gload16(pB0  + ko + 4096, lds + wb_ + ldsB0 + 4096u); \
    gload16(pB0l + ko,        lds + wb_ + 8192u + ldsB0); \
    gload16(pB0l + ko + 4096, lds + wb_ + 8192u + ldsB0 + 4096u); \
}

    // prologue: stage tile 0 (B via DMA, A via regs)
    {
        float4 a00 = *(const float4*)(fA0);
        float4 a01 = *(const float4*)(fA0 + 4);
        float4 a10 = *(const float4*)(fA1);
        float4 a11 = *(const float4*)(fA1 + 4);
        STGB1(0, 0);
        short8v h0, l0, h1, l1;
        cvt8(a00, a01, h0, l0);
        cvt8(a10, a11, h1, l1);
        *(short8v*)(lds + aw0)          = h0;
        *(short8v*)(lds + aw1)          = h1;
        *(short8v*)(lds + 8192u + aw0)  = l0;
        *(short8v*)(lds + 8192u + aw1)  = l1;
    }
    __syncthreads();

    #pragma unroll 1
    for (int kt = 0; kt < 1024; kt += 32) {
        const int par = (kt >> 5) & 1;
        const ushort_t* cpA = par ? pA1b : pA;
        const ushort_t* cpB = par ? pB1b : pB;
        const bool pf = (kt + 32) < 1024;

        float4 a00, a01, a10, a11;
        if (pf) {
            a00 = *(const float4*)(fA0 + kt + 32);
            a01 = *(const float4*)(fA0 + kt + 36);
            a10 = *(const float4*)(fA1 + kt + 32);
            a11 = *(const float4*)(fA1 + kt + 36);
            STGB1(kt + 32, par ^ 1);
        }

        MFMA_TILE(cpA, cpB)

        if (pf) {
            unsigned wb = (unsigned)(par ^ 1) * 32768u;
            short8v h0, l0, h1, l1;
            cvt8(a00, a01, h0, l0);
            cvt8(a10, a11, h1, l1);
            *(short8v*)(lds + wb + aw0)          = h0;
            *(short8v*)(lds + wb + aw1)          = h1;
            *(short8v*)(lds + wb + 8192u + aw0)  = l0;
            *(short8v*)(lds + wb + 8192u + aw1)  = l1;
        }
        __syncthreads();
    }

    // epilogue: 32x32 C/D: col = lane&31, row = (r&3)+8*(r>>2)+4*lk  [m74/m101; r6-verified]
    // write H in PLANE-MAJOR: idx = (row>>8)*RBLK + (col>>5)*KTBLK + ((col>>3)&3)*PLANE + (row&255)*8 + (col&7)
    #pragma unroll
    for (int i = 0; i < 4; ++i)
        #pragma unroll
        for (int j = 0; j < 2; ++j)
            #pragma unroll
            for (int r = 0; r < 16; ++r) {
                int row = m0 + wr*128 + i*32 + (r & 3) + 8*(r >> 2) + 4*lk;
                int col = n0 + wc*64 + j*32 + l31;
                float t = tanhf(acc[i][j][r]);
                size_t idx = (size_t)(row >> 8)*RBLK + (size_t)(col >> 5)*KTBLK
                           + ((col >> 3) & 3)*PLANE + (row & 255)*8 + (col & 7);
                ushort_t h = f2bf(t);
                C_hi[idx] = h;
                C_lo[idx] = f2bf(t - bf2f(h));
            }
#undef STGB1
}

// ================= layer-2: 256x256 GEMM + tanh (32x32 MFMA, plane-major in, row-major out) ===
__global__ __launch_bounds__(512, 2) void k_gemm_l2(
    const ushort_t* __restrict__ Ap, const ushort_t* __restrict__ Btp,
    ushort_t* __restrict__ C_hi, ushort_t* __restrict__ C_lo,
    unsigned aDelta, unsigned bDelta)
{
    __shared__ ushort_t lds[65536];

    const int tid  = threadIdx.x;
    const int wave = tid >> 6, lane = tid & 63;
    const int wr = wave >> 2, wc = wave & 3;
    const int l31 = lane & 31, lk = lane >> 5;

    int nwg = gridDim.x;
    int id = blockIdx.x;
    if (!(nwg & 7)) { int cpx = nwg >> 3; id = (id & 7)*cpx + (id >> 3); }
    const int n0 = (id & 3) * 256;
    const int m0 = (id >> 2) * 256;

    const ushort_t* pA0 = Ap  + (size_t)(m0 >> 8)*RBLK + wave*512 + lane*8;
    const ushort_t* pA0l = pA0 + aDelta;
    const ushort_t* pB0 = Btp + (size_t)(n0 >> 8)*RBLK + wave*512 + lane*8;
    const ushort_t* pB0l = pB0 + bDelta;
    const unsigned ldsA0 = (unsigned)wave*512u;
    const unsigned ldsB0 = 16384u + (unsigned)wave*512u;

    const unsigned fbu = (unsigned)lk*PLANE + (unsigned)l31*8u;
    const ushort_t* pA = lds + fbu + (unsigned)wr*1024u;
    const ushort_t* pB = lds + fbu + (unsigned)wc*512u;
    const ushort_t* pA1b = pA + 32768u;
    const ushort_t* pB1b = pB + 32768u;

    f32x16 acc[4][2] = {};

#define STG2(KT, WB) { \
    unsigned wb_ = (unsigned)(WB) * 32768u; \
    unsigned ko = (unsigned)(KT) * 256u; \
    gload16(pA0  + ko,        lds + wb_ + ldsA0); \
    gload16(pA0  + ko + 4096, lds + wb_ + ldsA0 + 4096u); \
    gload16(pA0l + ko,        lds + wb_ + 8192u + ldsA0); \
    gload16(pA0l + ko + 4096, lds + wb_ + 8192u + ldsA0 + 4096u); \
    gload16(pB0  + ko,        lds + wb_ + ldsB0); \
    gload16(pB0  + ko + 4096, lds + wb_ + ldsB0 + 4096u); \
    gload16(pB0l + ko,        lds + wb_ + 8192u + ldsB0); \
    gload16(pB0l + ko + 4096, lds + wb_ + 8192u + ldsB0 + 4096u); \
}

    STG2(0, 0);
    __syncthreads();

    #pragma unroll 1
    for (int kt = 0; kt < 1024; kt += 32) {
        const int par = (kt >> 5) & 1;
        const ushort_t* cpA = par ? pA1b : pA;
        const ushort_t* cpB = par ? pB1b : pB;

        if (kt + 32 < 1024) STG2(kt + 32, par ^ 1);

        MFMA_TILE(cpA, cpB)

        __syncthreads();
    }

    // epilogue: row-major C (consumed by L3's 128^2 kernel)
    #pragma unroll
    for (int i = 0; i < 4; ++i)
        #pragma unroll
        for (int j = 0; j < 2; ++j)
            #pragma unroll
            for (int r = 0; r < 16; ++r) {
                int row = m0 + wr*128 + i*32 + (r & 3) + 8*(r >> 2) + 4*lk;
                int col = n0 + wc*64 + j*32 + l31;
                float t = tanhf(acc[i][j][r]);
                size_t idx = (size_t)row*1024 + col;
                ushort_t h = f2bf(t);
                C_hi[idx] = h;
                C_lo[idx] = f2bf(t - bf2f(h));
            }
#undef STG2
}

// ---------------- 128x128 split-bf16 MFMA GEMM + tanh (layer 3; row-major in) ----------------
__global__ __launch_bounds__(256, 2) void k_gemm_mfma(
    const ushort_t* __restrict__ A_hi, const ushort_t* __restrict__ A_lo,
    const ushort_t* __restrict__ Bt_hi, const ushort_t* __restrict__ Bt_lo,
    ushort_t* __restrict__ C_hi, ushort_t* __restrict__ C_lo,
    float* __restrict__ Cf,
    int N)
{
    const int K = 1024;
    __shared__ ushort_t lds[16384];

    const int tid  = threadIdx.x;
    const int wave = tid >> 6, lane = tid & 63;
    const int wr = wave >> 1, wc = wave & 1;

    int nwg = gridDim.x * gridDim.y;
    int id = blockIdx.y * gridDim.x + blockIdx.x;
    if (!(nwg & 7)) { int cpx = nwg >> 3; id = (id & 7)*cpx + (id >> 3); }
    const int m0 = (id / gridDim.x) * 128, n0 = (id % gridDim.x) * 128;

    f32x4 acc[4][4] = {};

    int srow[2], sq[2], slbase[2];
    #pragma unroll
    for (int r = 0; r < 2; ++r) {
        int row = wave*32 + r*16 + (lane >> 2);
        srow[r]   = row;
        sq[r]     = (lane & 3) ^ ((row >> 1) & 3);
        slbase[r] = wave*1024 + r*512;
    }

    const int fr = lane & 15, fq = lane >> 4;

    for (int kt = 0; kt < K; kt += 32) {
        __syncthreads();
        #pragma unroll
        for (int r = 0; r < 2; ++r) {
            size_t ga = (size_t)(m0 + srow[r]) * K + kt + sq[r]*8;
            size_t gb = (size_t)(n0 + srow[r]) * K + kt + sq[r]*8;
            gload16(A_hi  + ga, lds          + slbase[r]);
            gload16(A_lo  + ga, lds + 4096   + slbase[r]);
            gload16(Bt_hi + gb, lds + 8192   + slbase[r]);
            gload16(Bt_lo + gb, lds + 12288  + slbase[r]);
        }
        __syncthreads();

        short8v ah[4], al[4], bh[4], bl[4];
        #pragma unroll
        for (int i = 0; i < 4; ++i) {
            int rowa = wr*64 + i*16 + fr;
            int offa = rowa*32 + ((fq ^ ((rowa >> 1) & 3)) * 8);
            ah[i] = *(const short8v*)(lds + offa);
            al[i] = *(const short8v*)(lds + 4096 + offa);
            int rowb = wc*64 + i*16 + fr;
            int offb = rowb*32 + ((fq ^ ((rowb >> 1) & 3)) * 8);
            bh[i] = *(const short8v*)(lds + 8192 + offb);
            bl[i] = *(const short8v*)(lds + 12288 + offb);
        }
        #pragma unroll
        for (int i = 0; i < 4; ++i)
            #pragma unroll
            for (int j = 0; j < 4; ++j) {
                acc[i][j] = __builtin_amdgcn_mfma_f32_16x16x32_bf16(ah[i], bh[j], acc[i][j], 0, 0, 0);
                acc[i][j] = __builtin_amdgcn_mfma_f32_16x16x32_bf16(ah[i], bl[j], acc[i][j], 0, 0, 0);
                acc[i][j] = __builtin_amdgcn_mfma_f32_16x16x32_bf16(al[i], bh[j], acc[i][j], 0, 0, 0);
            }
    }

    #pragma unroll
    for (int i = 0; i < 4; ++i)
        #pragma unroll
        for (int j = 0; j < 4; ++j)
            #pragma unroll
            for (int r = 0; r < 4; ++r) {
                int row = m0 + wr*64 + i*16 + fq*4 + r;
                int col = n0 + wc*64 + j*16 + fr;
                float t = tanhf(acc[i][j][r]);
                size_t idx = (size_t)row*N + col;
                if (Cf) Cf[idx] = t;
                if (C_hi) {
                    ushort_t h = f2bf(t);
                    C_hi[idx] = h;
                    C_lo[idx] = f2bf(t - bf2f(h));
                }
            }
}

// ---------------- MFMA assignment + fused histogram ----------------
__global__ __launch_bounds__(256) void k_assign_mfma(
    const ushort_t* __restrict__ SEh, const ushort_t* __restrict__ SEl,
    const ushort_t* __restrict__ ch, const ushort_t* __restrict__ cl,
    const float* __restrict__ c2,
    int* __restrict__ sc, float* __restrict__ out_w,
    int* __restrict__ blockHist)
{
    __shared__ ushort_t lds[16384];
    __shared__ float c2s[512];
    __shared__ float redD[128][2];
    __shared__ int   redI[128][2];

    const int modal = blockIdx.y;
    const int t0 = blockIdx.x * 128;
    const int tid  = threadIdx.x;
    const int wave = tid >> 6, lane = tid & 63;
    const int wr = wave >> 1, wc = wave & 1;
    const int fr = lane & 15, fq = lane >> 4;

    const ushort_t* seh = SEh + (size_t)modal * NTOK * 256;
    const ushort_t* sel = SEl + (size_t)modal * NTOK * 256;

    c2s[tid] = c2[tid];
    c2s[tid + 256] = c2[tid + 256];

    int srow[2], sq[2], slbase[2];
    #pragma unroll
    for (int r = 0; r < 2; ++r) {
        int row = wave*32 + r*16 + (lane >> 2);
        srow[r]   = row;
        sq[r]     = (lane & 3) ^ ((row >> 1) & 3);
        slbase[r] = wave*1024 + r*512;
    }

    float bd[16]; int bi[16];
    #pragma unroll
    for (int s = 0; s < 16; ++s) { bd[s] = 3.4e38f; bi[s] = 0; }

    for (int j = 0; j < 4; ++j) {
        f32x4 acc[4][4] = {};
        for (int kt = 0; kt < 256; kt += 32) {
            __syncthreads();
            #pragma unroll
            for (int r = 0; r < 2; ++r) {
                size_t ga = (size_t)(t0 + srow[r]) * 256 + kt + sq[r]*8;
                size_t gc = (size_t)(j*128 + srow[r]) * 256 + kt + sq[r]*8;
                gload16(seh + ga, lds          + slbase[r]);
                gload16(sel + ga, lds + 4096   + slbase[r]);
                gload16(ch  + gc, lds + 8192   + slbase[r]);
                gload16(cl  + gc, lds + 12288  + slbase[r]);
            }
            __syncthreads();

            short8v ah[4], al[4], bh[4], bl[4];
            #pragma unroll
            for (int i = 0; i < 4; ++i) {
                int rowa = wr*64 + i*16 + fr;
                int offa = rowa*32 + ((fq ^ ((rowa >> 1) & 3)) * 8);
                ah[i] = *(const short8v*)(lds + offa);
                al[i] = *(const short8v*)(lds + 4096 + offa);
                int rowb = wc*64 + i*16 + fr;
                int offb = rowb*32 + ((fq ^ ((rowb >> 1) & 3)) * 8);
                bh[i] = *(const short8v*)(lds + 8192 + offb);
                bl[i] = *(const short8v*)(lds + 12288 + offb);
            }
            #pragma unroll
            for (int i = 0; i < 4; ++i)
                #pragma unroll
                for (int jj = 0; jj < 4; ++jj) {
                    acc[i][jj] = __builtin_amdgcn_mfma_f32_16x16x32_bf16(ah[i], bh[jj], acc[i][jj], 0, 0, 0);
                    acc[i][jj] = __builtin_amdgcn_mfma_f32_16x16x32_bf16(ah[i], bl[jj], acc[i][jj], 0, 0, 0);
                    acc[i][jj] = __builtin_amdgcn_mfma_f32_16x16x32_bf16(al[i], bh[jj], acc[i][jj], 0, 0, 0);
                }
        }
        #pragma unroll
        for (int i = 0; i < 4; ++i)
            #pragma unroll
            for (int jj = 0; jj < 4; ++jj) {
                int col = j*128 + wc*64 + jj*16 + fr;
                float cc = c2s[col];
                #pragma unroll
                for (int r = 0; r < 4; ++r) {
                    float d = cc - 2.f * acc[i][jj][r];
                    int s = i*4 + r;
                    if (d < bd[s]) { bd[s] = d; bi[s] = col; }
                }
            }
    }

    #pragma unroll
    for (int s = 0; s < 16; ++s) {
        #pragma unroll
        for (int off = 1; off < 16; off <<= 1) {
            float od = __shfl_xor(bd[s], off);
            int   oi = __shfl_xor(bi[s], off);
            if (od < bd[s] || (od == bd[s] && oi < bi[s])) { bd[s] = od; bi[s] = oi; }
        }
    }
    if (fr == 0) {
        #pragma unroll
        for (int i = 0; i < 4; ++i)
            #pragma unroll
            for (int r = 0; r < 4; ++r) {
                int tl = wr*64 + i*16 + fq*4 + r;
                redD[tl][wc] = bd[i*4 + r];
                redI[tl][wc] = bi[i*4 + r];
            }
    }
    __syncthreads();
    if (tid < 128) {
        float d0 = redD[tid][0], d1 = redD[tid][1];
        int   i0 = redI[tid][0], i1 = redI[tid][1];
        if (d1 < d0 || (d1 == d0 && i1 < i0)) { d0 = d1; i0 = i1; }
        int g = t0 + tid;
        sc[modal*NTOK + g] = i0;
        out_w[OFF_SC + (size_t)modal*NTOK + g] = (float)i0;
        atomicAdd(&blockHist[(modal*128 + (g >> 8))*512 + i0], 1);
    }
}

// ---------------- fp32 fallback assignment + fused histogram ----------------
__global__ __launch_bounds__(256) void k_assign(
    const float* __restrict__ out_ro,
    const float* __restrict__ c2,
    int* __restrict__ sc,
    float* __restrict__ out_w,
    int* __restrict__ blockHist)
{
    const int modal = blockIdx.y;
    const int tok0 = blockIdx.x * 64;
    const float* se   = out_ro + OFF_SE + (size_t)modal * NTOK * 256;
    const float* cent = out_ro + OFF_CENT;

    __shared__ float4 se4[64][64];
    __shared__ float4 ct4[64][64];

    const int tid = threadIdx.x;
    const int tt = tid & 15, cc = tid >> 4;

    {
        int rbase = tid >> 6;
        int d4 = tid & 63;
        #pragma unroll
        for (int i = 0; i < 16; ++i) {
            int t = i*4 + rbase;
            float4 v = *(const float4*)(se + (size_t)(tok0 + t)*256 + d4*4);
            se4[t][d4 ^ (t >> 2)] = v;
        }
    }
    __syncthreads();

    float e2r[4];
    #pragma unroll
    for (int k2 = 0; k2 < 4; ++k2) {
        float s = 0.f;
        for (int d4 = 0; d4 < 64; ++d4) {
            float4 v = se4[4*tt + k2][d4 ^ tt];
            s += dot4(v, v);
        }
        e2r[k2] = s;
    }

    float bd[4]; int bi[4];
    #pragma unroll
    for (int k2 = 0; k2 < 4; ++k2) { bd[k2] = 3.4e38f; bi[k2] = 0; }

    for (int ctile = 0; ctile < 8; ++ctile) {
        int c0 = ctile * 64;
        {
            int rbase = tid >> 6;
            int d4 = tid & 63;
            #pragma unroll
            for (int i = 0; i < 16; ++i) {
                int r = i*4 + rbase;
                float4 v = *(const float4*)(cent + (size_t)(c0 + r)*256 + d4*4);
                ct4[r][d4 ^ (r >> 2)] = v;
            }
        }
        __syncthreads();

        float accd[4][4];
        #pragma unroll
        for (int a = 0; a < 4; ++a)
            #pragma unroll
            for (int b = 0; b < 4; ++b) accd[a][b] = 0.f;

        for (int d4 = 0; d4 < 64; ++d4) {
            float4 sv[4], cv[4];
            #pragma unroll
            for (int k2 = 0; k2 < 4; ++k2) sv[k2] = se4[4*tt + k2][d4 ^ tt];
            #pragma unroll
            for (int jx = 0; jx < 4; ++jx) cv[jx] = ct4[4*cc + jx][d4 ^ cc];
            #pragma unroll
            for (int k2 = 0; k2 < 4; ++k2)
                #pragma unroll
                for (int jx = 0; jx < 4; ++jx)
                    accd[k2][jx] += dot4(sv[k2], cv[jx]);
        }

        #pragma unroll
        for (int jx = 0; jx < 4; ++jx) {
            int cidx = c0 + 4*cc + jx;
            float cj = c2[cidx];
            #pragma unroll
            for (int k2 = 0; k2 < 4; ++k2) {
                float d = cj + e2r[k2] - 2.f * accd[k2][jx];
                if (d < bd[k2]) { bd[k2] = d; bi[k2] = cidx; }
            }
        }
        __syncthreads();
    }

    float* red_d = (float*)ct4;
    int*   red_i = (int*)ct4 + 64*17;
    #pragma unroll
    for (int k2 = 0; k2 < 4; ++k2) {
        red_d[(4*tt + k2)*17 + cc] = bd[k2];
        red_i[(4*tt + k2)*17 + cc] = bi[k2];
    }
    __syncthreads();
    if (tid < 64) {
        float b = red_d[tid*17]; int ix = red_i[tid*17];
        #pragma unroll
        for (int q = 1; q < 16; ++q) {
            float d = red_d[tid*17 + q]; int i2 = red_i[tid*17 + q];
            if (d < b || (d == b && i2 < ix)) { b = d; ix = i2; }
        }
        int g = tok0 + tid;
        sc[modal*NTOK + g] = ix;
        out_w[OFF_SC + (size_t)modal*NTOK + g] = (float)ix;
        atomicAdd(&blockHist[(modal*128 + (g >> 8))*512 + ix], 1);
    }
}

// ---------------- per-class block scan + class exclusive scan ----------------
__global__ __launch_bounds__(512) void k_scan(const int* __restrict__ blockHist,
                                              int* __restrict__ blockBase,
                                              int* __restrict__ classBase,
                                              float* __restrict__ out)
{
    int modal = blockIdx.x;
    int c = threadIdx.x;
    int run = 0;
    for (int b = 0; b < 128; ++b) {
        int idx = (modal*128 + b)*512 + c;
        blockBase[idx] = run;
        run += blockHist[idx];
    }
    float* cnt = out + (modal ? OFF_CI : OFF_CT);
    cnt[c] = (float)run;

    __shared__ int s[512];
    s[c] = run;
    __syncthreads();
    int total = run;
    for (int off = 1; off < 512; off <<= 1) {
        int v = 0;
        if (c >= off) v = s[c - off];
        __syncthreads();
        s[c] += v;
        __syncthreads();
    }
    classBase[modal*512 + c] = s[c] - total;
}

__global__ __launch_bounds__(256) void k_scatter(const int* __restrict__ sc,
                                                 const int* __restrict__ blockBase,
                                                 const int* __restrict__ classBase,
                                                 float* __restrict__ out)
{
    int modal = blockIdx.y, blk = blockIdx.x, tid = threadIdx.x;
    __shared__ int cls[256];
    int t = blk*256 + tid;
    int c = sc[modal*NTOK + t];
    cls[tid] = c;
    __syncthreads();
    int rank = 0;
    for (int j = 0; j < tid; ++j) rank += (cls[j] == c) ? 1 : 0;
    int pos = classBase[modal*512 + c] + blockBase[(modal*128 + blk)*512 + c] + rank;
    float* oo = out + (modal ? OFF_OI : OFF_OT);
    oo[pos] = (float)t;
}

extern "C" void kernel_launch(void* const* d_in, const int* in_sizes, int n_in,
                              void* d_out, int out_size, void* d_ws, size_t ws_size,
                              hipStream_t stream)
{
    const float* text_emb  = (const float*)d_in[0];
    const float* image_emb = (const float*)d_in[1];
    const float* W[2][3] = {
        {(const float*)d_in[2], (const float*)d_in[3], (const float*)d_in[4]},
        {(const float*)d_in[5], (const float*)d_in[6], (const float*)d_in[7]}
    };
    const float* cent_raw = (const float*)d_in[8];
    float* out = (float*)d_out;
    char* w = (char*)d_ws;

    int*   sc        = (int*)w;
    int*   blockHist = (int*)(w + 0x40000);
    int*   blockBase = (int*)(w + 0xC0000);
    int*   classBase = (int*)(w + 0x140000);
    float* c2        = (float*)(w + 0x141000);
    ushort_t* cent_h = (ushort_t*)(w + 0x142000);
    ushort_t* cent_l = (ushort_t*)(w + 0x182000);

    ushort_t* wreg = (ushort_t*)(w + 0x200000);
    const size_t WM = 4*1048576 + 2*262144;

    ushort_t* SEh = (ushort_t*)(w + 0x1400000);
    ushort_t* SEl = (ushort_t*)(w + 0x3400000);

    bool mfmaAssign = true;
    size_t actoff = 0x5400000;
    int Mc = 0;
    for (int c = NTOK; c >= 256; c >>= 1)
        if (actoff + (size_t)c*8192 <= ws_size) { Mc = c; break; }
    if (Mc == 0) {
        mfmaAssign = false;
        actoff = 0x1400000;
        for (int c = NTOK; c >= 256; c >>= 1)
            if (actoff + (size_t)c*8192 <= ws_size) { Mc = c; break; }
        if (Mc == 0) Mc = 256;
    }
    ushort_t* act = (ushort_t*)(w + actoff);

    // zero the fused histogram (deterministic every call)
    hipMemsetAsync(blockHist, 0, 2*128*512*sizeof(int), stream);

    k_cent<<<dim3(512), dim3(64), 0, stream>>>(cent_raw, out, c2, cent_h, cent_l);
    k_prep<<<dim3(4672), dim3(256), 0, stream>>>(
        W[0][0], W[0][1], W[0][2], W[1][0], W[1][1], W[1][2], wreg, out);

    for (int m = 0; m < 2; ++m) {
        const float* emb = m ? image_emb : text_emb;
        ushort_t* w1h = wreg + (size_t)m*WM;
        ushort_t* w2h = w1h + 2*1048576;
        ushort_t* w3h = w1h + 4*1048576;
        ushort_t* w3l = w3h + 262144;

        ushort_t* Ah = act;
        ushort_t* Al = Ah + (size_t)Mc*1024;
        ushort_t* Hh = Al + (size_t)Mc*1024;
        ushort_t* Hl = Hh + (size_t)Mc*1024;

        for (int s0 = 0; s0 < NTOK; s0 += Mc) {
            // L1: fused fp32 split + GEMM (32x32, plane-major out)
            k_gemm_l1<<<dim3((Mc/256)*4), dim3(512), 0, stream>>>(
                emb + (size_t)s0*1024, w1h, Hh, Hl, 1048576u);
            // L2: plane-major in, row-major out (32x32)
            k_gemm_l2<<<dim3((Mc/256)*4), dim3(512), 0, stream>>>(
                Hh, w2h, Ah, Al, (unsigned)Mc*1024u, 1048576u);
            // L3: row-major 128^2 kernel (unchanged)
            ushort_t* seh_ptr = mfmaAssign ? SEh + ((size_t)m*NTOK + s0)*256 : nullptr;
            ushort_t* sel_ptr = mfmaAssign ? SEl + ((size_t)m*NTOK + s0)*256 : nullptr;
            k_gemm_mfma<<<dim3(2, Mc/128), dim3(256), 0, stream>>>(
                Ah, Al, w3h, w3l, seh_ptr, sel_ptr,
                out + OFF_SE + ((size_t)m*NTOK + s0)*256, 256);
        }
    }

    if (mfmaAssign) {
        k_assign_mfma<<<dim3(256, 2), dim3(256), 0, stream>>>(
            SEh, SEl, cent_h, cent_l, c2, sc, out, blockHist);
    } else {
        k_assign<<<dim3(512, 2), dim3(256), 0, stream>>>(out, c2, sc, out, blockHist);
    }
    k_scan   <<<dim3(2),      dim3(512), 0, stream>>>(blockHist, blockBase, classBase, out);
    k_scatter<<<dim3(128, 2), dim3(256), 0, stream>>>(sc, blockBase, classBase, out);
}

// Round 11
// 1030.319 us; speedup vs baseline: 1.0871x; 1.0871x over previous
//
#include <hip/hip_runtime.h>
#include <math.h>

#define NTOK 32768
typedef unsigned short ushort_t;

// d_out offsets (in floats)
#define OFF_CENT 0
#define OFF_SE   131072
#define OFF_WC   16908288
#define OFF_SC   16973824
#define OFF_OT   17039360
#define OFF_CT   17072128
#define OFF_OI   17072640
#define OFF_CI   17105408

typedef __attribute__((ext_vector_type(8))) short short8v;
typedef __attribute__((ext_vector_type(4))) float f32x4;

__device__ __forceinline__ float dot4(float4 a, float4 b){
    return a.x*b.x + a.y*b.y + a.z*b.z + a.w*b.w;
}

// RNE float -> bf16 bits
__device__ __forceinline__ ushort_t f2bf(float x){
    unsigned int u = __float_as_uint(x);
    unsigned int r = (u + 0x7fffu + ((u >> 16) & 1u)) >> 16;
    return (ushort_t)r;
}
__device__ __forceinline__ float bf2f(ushort_t h){
    return __uint_as_float(((unsigned int)h) << 16);
}

__device__ __forceinline__ void gload16(const void* g, void* l){
    __builtin_amdgcn_global_load_lds(
        (const __attribute__((address_space(1))) void*)g,
        (__attribute__((address_space(3))) void*)l,
        16, 0, 0);
}

// split 8 fp32 -> 8 bf16 hi + 8 bf16 lo (bit-identical to esplit)
__device__ __forceinline__ void cvt8(float4 a, float4 b, short8v& h, short8v& l){
    float x[8] = {a.x, a.y, a.z, a.w, b.x, b.y, b.z, b.w};
    #pragma unroll
    for (int i = 0; i < 8; ++i) {
        ushort_t hh = f2bf(x[i]);
        h[i] = (short)hh;
        l[i] = (short)f2bf(x[i] - bf2f(hh));
    }
}

// ---------------- centroids: tanh + c2 + hi/lo split ----------------
__global__ __launch_bounds__(64) void k_cent(const float* __restrict__ raw,
                                             float* __restrict__ out,
                                             float* __restrict__ c2,
                                             ushort_t* __restrict__ ch,
                                             ushort_t* __restrict__ cl)
{
    int c = blockIdx.x, l = threadIdx.x;
    float4 v = *(const float4*)(raw + (size_t)c*256 + l*4);
    float4 t;
    t.x = tanhf(v.x); t.y = tanhf(v.y); t.z = tanhf(v.z); t.w = tanhf(v.w);
    *(float4*)(out + OFF_CENT + (size_t)c*256 + l*4) = t;
    ushort4 h = make_ushort4(f2bf(t.x), f2bf(t.y), f2bf(t.z), f2bf(t.w));
    ushort4 lo = make_ushort4(f2bf(t.x - bf2f(h.x)), f2bf(t.y - bf2f(h.y)),
                              f2bf(t.z - bf2f(h.z)), f2bf(t.w - bf2f(h.w)));
    *(ushort4*)(ch + (size_t)c*256 + l*4) = h;
    *(ushort4*)(cl + (size_t)c*256 + l*4) = lo;
    float s = dot4(t, t);
    #pragma unroll
    for (int off = 32; off > 0; off >>= 1) s += __shfl_down(s, off);
    if (l == 0) c2[c] = s;
}

// ---------------- emb split (fallback path only) ----------------
__global__ __launch_bounds__(256) void k_esplit(const float* __restrict__ x,
                                                ushort_t* __restrict__ hi,
                                                ushort_t* __restrict__ lo,
                                                long n4)
{
    long g = (long)blockIdx.x*256 + threadIdx.x;
    if (g >= n4) return;
    float4 v = ((const float4*)x)[g];
    ushort_t h0 = f2bf(v.x), h1 = f2bf(v.y), h2 = f2bf(v.z), h3 = f2bf(v.w);
    ushort4 h = make_ushort4(h0, h1, h2, h3);
    ushort4 l = make_ushort4(f2bf(v.x - bf2f(h0)), f2bf(v.y - bf2f(h1)),
                             f2bf(v.z - bf2f(h2)), f2bf(v.w - bf2f(h3)));
    ((ushort4*)hi)[g] = h;
    ((ushort4*)lo)[g] = l;
}

// ---------------- weight transpose + split (device body, row-major [N][K]) ----------------
__device__ __forceinline__ void wsplit_tile(const float* __restrict__ W,
                                            ushort_t* __restrict__ Wt_hi,
                                            ushort_t* __restrict__ Wt_lo,
                                            int K, int N, int bx, int by)
{
    __shared__ float t[32][33];
    int k0 = by*32, n0 = bx*32;
    int tx = threadIdx.x & 31, ty = threadIdx.x >> 5;
    #pragma unroll
    for (int r = 0; r < 4; ++r)
        t[ty + r*8][tx] = W[(size_t)(k0 + ty + r*8)*N + n0 + tx];
    __syncthreads();
    #pragma unroll
    for (int r = 0; r < 4; ++r) {
        int n = ty + r*8;
        float x = t[tx][n];
        ushort_t h = f2bf(x);
        Wt_hi[(size_t)(n0+n)*K + k0 + tx] = h;
        Wt_lo[(size_t)(n0+n)*K + k0 + tx] = f2bf(x - bf2f(h));
    }
}

// ---------------- combined prep: all 6 weight splits + word_class ----------------
__global__ __launch_bounds__(256) void k_prep(
    const float* __restrict__ W1t, const float* __restrict__ W2t, const float* __restrict__ W3t,
    const float* __restrict__ W1i, const float* __restrict__ W2i, const float* __restrict__ W3i,
    ushort_t* __restrict__ wreg, float* __restrict__ out)
{
    const size_t WM = 4*1048576 + 2*262144;
    int b = blockIdx.x;
    if (b >= 4608) {
        int g = (b - 4608)*256 + threadIdx.x;
        float v = (g*4 < NTOK) ? 0.f : 1.f;
        ((float4*)(out + OFF_WC))[g] = make_float4(v, v, v, v);
        return;
    }
    int m = b / 2304;
    int r = b % 2304;
    ushort_t* base = wreg + (size_t)m*WM;
    const float* Ws[3][2] = {{W1t, W1i}, {W2t, W2i}, {W3t, W3i}};
    if (r < 1024) {
        wsplit_tile(Ws[0][m], base, base + 1048576, 1024, 1024, r % 32, r / 32);
    } else if (r < 2048) {
        int r2 = r - 1024;
        wsplit_tile(Ws[1][m], base + 2*1048576, base + 3*1048576, 1024, 1024, r2 % 32, r2 / 32);
    } else {
        int r3 = r - 2048;
        wsplit_tile(Ws[2][m], base + 4*1048576, base + 4*1048576 + 262144, 1024, 256, r3 % 8, r3 / 8);
    }
}

// ================= layer-1: fused fp32-A split + 256x256 split-bf16 GEMM + tanh ======
__global__ __launch_bounds__(512, 2) void k_gemm_l1(
    const float* __restrict__ Af, const ushort_t* __restrict__ Bt_hi,
    ushort_t* __restrict__ C_hi, ushort_t* __restrict__ C_lo,
    unsigned bDelta, int N)
{
    __shared__ ushort_t lds[65536];   // 2 x { Ah Al Bh Bl } each [256][32]

    const int tid  = threadIdx.x;
    const int wave = tid >> 6, lane = tid & 63;
    const int wr = wave >> 2, wc = wave & 3;
    const int fr = lane & 15, fq = lane >> 4;

    int nwg = gridDim.x;
    int id = blockIdx.x;
    if (!(nwg & 7)) { int cpx = nwg >> 3; id = (id & 7)*cpx + (id >> 3); }
    const int nx = N >> 8;
    const int n0 = (id % nx) * 256;
    const int m0 = (id / nx) * 256;

    const int srow0 = tid >> 2;
    const int qx = (tid & 3) ^ ((srow0 >> 1) & 3);

    const float* fA0 = Af + (size_t)(m0 + srow0) * 1024 + qx*8;
    const float* fA1 = fA0 + 131072;
    const unsigned offB0 = (unsigned)(n0 + srow0) * 1024u + (unsigned)qx * 8u;
    const ushort_t* pB0  = Bt_hi + offB0;
    const ushort_t* pB1  = pB0 + 131072u;
    const ushort_t* pB0l = pB0 + bDelta;
    const ushort_t* pB1l = pB1 + bDelta;
    const unsigned ldsS0 = (unsigned)wave * 512u;
    const unsigned ldsS1 = ldsS0 + 4096u;
    const unsigned wOff  = ldsS0 + (unsigned)lane * 8u;

    const unsigned fb = (unsigned)fr*32u + (unsigned)((fq ^ ((fr >> 1) & 3)) * 8);
    const ushort_t* p0 = lds + fb;
    const ushort_t* p1 = p0 + 32768u;

    f32x4 acc[8][4] = {};

#define STGB(KT, WB) { \
    unsigned wb_ = (unsigned)(WB) * 32768u; \
    gload16(pB0  + (KT), lds + wb_ + 16384u + ldsS0); \
    gload16(pB1  + (KT), lds + wb_ + 16384u + ldsS1); \
    gload16(pB0l + (KT), lds + wb_ + 24576u + ldsS0); \
    gload16(pB1l + (KT), lds + wb_ + 24576u + ldsS1); \
}
#define RA1(P, hl, i) (*(const short8v*)((P) + (hl)*8192u + (unsigned)wr*4096u + (unsigned)(i)*512u))
#define RB1(P, hl, j) (*(const short8v*)((P) + 16384u + (hl)*8192u + (unsigned)wc*2048u + (unsigned)(j)*512u))
#define MM16(A8, B8, C4) __builtin_amdgcn_mfma_f32_16x16x32_bf16(A8, B8, C4, 0, 0, 0)

    {
        float4 a00 = *(const float4*)(fA0);
        float4 a01 = *(const float4*)(fA0 + 4);
        float4 a10 = *(const float4*)(fA1);
        float4 a11 = *(const float4*)(fA1 + 4);
        STGB(0, 0);
        short8v h0, l0, h1, l1;
        cvt8(a00, a01, h0, l0);
        cvt8(a10, a11, h1, l1);
        *(short8v*)(lds + wOff)          = h0;
        *(short8v*)(lds + 4096u + wOff)  = h1;
        *(short8v*)(lds + 8192u + wOff)  = l0;
        *(short8v*)(lds + 12288u + wOff) = l1;
    }
    __syncthreads();

    #pragma unroll 1
    for (int kt = 0; kt < 1024; kt += 32) {
        const int par = (kt >> 5) & 1;
        const ushort_t* cp = par ? p1 : p0;
        const bool pf = (kt + 32) < 1024;

        float4 a00, a01, a10, a11;
        if (pf) {
            a00 = *(const float4*)(fA0 + kt + 32);
            a01 = *(const float4*)(fA0 + kt + 36);
            a10 = *(const float4*)(fA1 + kt + 32);
            a11 = *(const float4*)(fA1 + kt + 36);
            STGB(kt + 32, par ^ 1);
        }

        short8v bh0 = RB1(cp,0,0), bl0 = RB1(cp,1,0);
        short8v bh1 = RB1(cp,0,1), bl1 = RB1(cp,1,1);
        short8v bh2 = RB1(cp,0,2), bl2 = RB1(cp,1,2);
        short8v bh3 = RB1(cp,0,3), bl3 = RB1(cp,1,3);

        __builtin_amdgcn_s_setprio(1);
        #pragma unroll
        for (int i = 0; i < 8; ++i) {
            short8v ah = RA1(cp,0,i), al = RA1(cp,1,i);
            acc[i][0] = MM16(ah, bh0, acc[i][0]);
            acc[i][1] = MM16(ah, bh1, acc[i][1]);
            acc[i][2] = MM16(ah, bh2, acc[i][2]);
            acc[i][3] = MM16(ah, bh3, acc[i][3]);
            acc[i][0] = MM16(ah, bl0, acc[i][0]);
            acc[i][1] = MM16(ah, bl1, acc[i][1]);
            acc[i][2] = MM16(ah, bl2, acc[i][2]);
            acc[i][3] = MM16(ah, bl3, acc[i][3]);
            acc[i][0] = MM16(al, bh0, acc[i][0]);
            acc[i][1] = MM16(al, bh1, acc[i][1]);
            acc[i][2] = MM16(al, bh2, acc[i][2]);
            acc[i][3] = MM16(al, bh3, acc[i][3]);
        }
        __builtin_amdgcn_s_setprio(0);

        if (pf) {
            unsigned wb = (unsigned)(par ^ 1) * 32768u;
            short8v h0, l0, h1, l1;
            cvt8(a00, a01, h0, l0);
            cvt8(a10, a11, h1, l1);
            *(short8v*)(lds + wb + wOff)          = h0;
            *(short8v*)(lds + wb + 4096u + wOff)  = h1;
            *(short8v*)(lds + wb + 8192u + wOff)  = l0;
            *(short8v*)(lds + wb + 12288u + wOff) = l1;
        }
        __syncthreads();
    }

    #pragma unroll
    for (int i = 0; i < 8; ++i)
        #pragma unroll
        for (int j = 0; j < 4; ++j)
            #pragma unroll
            for (int r = 0; r < 4; ++r) {
                int row = m0 + wr*128 + i*16 + fq*4 + r;
                int col = n0 + wc*64 + j*16 + fr;
                float t = tanhf(acc[i][j][r]);
                size_t idx = (size_t)row*N + col;
                ushort_t h = f2bf(t);
                C_hi[idx] = h;
                C_lo[idx] = f2bf(t - bf2f(h));
            }
#undef STGB
#undef RA1
#undef RB1
#undef MM16
}

// ================= 256x256 8-wave split-bf16 GEMM + tanh, 16x16x32 MFMA ==========
__global__ __launch_bounds__(512, 2) void k_gemm_mfma256(
    const ushort_t* __restrict__ A_hi, const ushort_t* __restrict__ Bt_hi,
    ushort_t* __restrict__ C_hi, ushort_t* __restrict__ C_lo,
    unsigned aDelta, unsigned bDelta, int N)
{
    __shared__ ushort_t lds[65536];

    const int tid  = threadIdx.x;
    const int wave = tid >> 6, lane = tid & 63;
    const int wr = wave >> 2, wc = wave & 3;
    const int fr = lane & 15, fq = lane >> 4;

    int nwg = gridDim.x;
    int id = blockIdx.x;
    if (!(nwg & 7)) { int cpx = nwg >> 3; id = (id & 7)*cpx + (id >> 3); }
    const int nx = N >> 8;
    const int n0 = (id % nx) * 256;
    const int m0 = (id / nx) * 256;

    const int srow0 = tid >> 2;
    const int qx = (tid & 3) ^ ((srow0 >> 1) & 3);

    const unsigned offA0 = (unsigned)(m0 + srow0) * 1024u + (unsigned)qx * 8u;
    const unsigned offB0 = (unsigned)(n0 + srow0) * 1024u + (unsigned)qx * 8u;
    const ushort_t* pA0  = A_hi + offA0;
    const ushort_t* pA1  = pA0 + 131072u;
    const ushort_t* pA0l = pA0 + aDelta;
    const ushort_t* pA1l = pA1 + aDelta;
    const ushort_t* pB0  = Bt_hi + offB0;
    const ushort_t* pB1  = pB0 + 131072u;
    const ushort_t* pB0l = pB0 + bDelta;
    const ushort_t* pB1l = pB1 + bDelta;
    const unsigned ldsS0 = (unsigned)wave * 512u;
    const unsigned ldsS1 = ldsS0 + 4096u;

    const unsigned fb = (unsigned)fr*32u + (unsigned)((fq ^ ((fr >> 1) & 3)) * 8);
    const ushort_t* p0 = lds + fb;
    const ushort_t* p1 = p0 + 32768u;

    f32x4 acc[8][4] = {};

#define STG(KT, WB) { \
    unsigned wb_ = (unsigned)(WB) * 32768u; \
    gload16(pA0  + (KT), lds + wb_ +           ldsS0); \
    gload16(pA1  + (KT), lds + wb_ +           ldsS1); \
    gload16(pA0l + (KT), lds + wb_ +  8192u +  ldsS0); \
    gload16(pA1l + (KT), lds + wb_ +  8192u +  ldsS1); \
    gload16(pB0  + (KT), lds + wb_ + 16384u +  ldsS0); \
    gload16(pB1  + (KT), lds + wb_ + 16384u +  ldsS1); \
    gload16(pB0l + (KT), lds + wb_ + 24576u +  ldsS0); \
    gload16(pB1l + (KT), lds + wb_ + 24576u +  ldsS1); \
}
#define RA(P, hl, i) (*(const short8v*)((P) + (hl)*8192u + (unsigned)wr*4096u + (unsigned)(i)*512u))
#define RB(P, hl, j) (*(const short8v*)((P) + 16384u + (hl)*8192u + (unsigned)wc*2048u + (unsigned)(j)*512u))
#define MM16(A8, B8, C4) __builtin_amdgcn_mfma_f32_16x16x32_bf16(A8, B8, C4, 0, 0, 0)

    STG(0, 0);
    __syncthreads();

    #pragma unroll 1
    for (int kt = 0; kt < 1024; kt += 32) {
        const int par = (kt >> 5) & 1;
        const ushort_t* cp = par ? p1 : p0;

        short8v bh0 = RB(cp,0,0), bl0 = RB(cp,1,0);
        short8v bh1 = RB(cp,0,1), bl1 = RB(cp,1,1);
        short8v bh2 = RB(cp,0,2), bl2 = RB(cp,1,2);
        short8v bh3 = RB(cp,0,3), bl3 = RB(cp,1,3);

        if (kt + 32 < 1024) STG(kt + 32, par ^ 1);

        __builtin_amdgcn_s_setprio(1);
        #pragma unroll
        for (int i = 0; i < 8; ++i) {
            short8v ah = RA(cp,0,i), al = RA(cp,1,i);
            acc[i][0] = MM16(ah, bh0, acc[i][0]);
            acc[i][1] = MM16(ah, bh1, acc[i][1]);
            acc[i][2] = MM16(ah, bh2, acc[i][2]);
            acc[i][3] = MM16(ah, bh3, acc[i][3]);
            acc[i][0] = MM16(ah, bl0, acc[i][0]);
            acc[i][1] = MM16(ah, bl1, acc[i][1]);
            acc[i][2] = MM16(ah, bl2, acc[i][2]);
            acc[i][3] = MM16(ah, bl3, acc[i][3]);
            acc[i][0] = MM16(al, bh0, acc[i][0]);
            acc[i][1] = MM16(al, bh1, acc[i][1]);
            acc[i][2] = MM16(al, bh2, acc[i][2]);
            acc[i][3] = MM16(al, bh3, acc[i][3]);
        }
        __builtin_amdgcn_s_setprio(0);

        __syncthreads();
    }

    #pragma unroll
    for (int i = 0; i < 8; ++i)
        #pragma unroll
        for (int j = 0; j < 4; ++j)
            #pragma unroll
            for (int r = 0; r < 4; ++r) {
                int row = m0 + wr*128 + i*16 + fq*4 + r;
                int col = n0 + wc*64 + j*16 + fr;
                float t = tanhf(acc[i][j][r]);
                size_t idx = (size_t)row*N + col;
                ushort_t h = f2bf(t);
                C_hi[idx] = h;
                C_lo[idx] = f2bf(t - bf2f(h));
            }
#undef STG
#undef RA
#undef RB
#undef MM16
}

// ---------- layer-3: 128x128 split-bf16 GEMM + tanh, free-run double-buffered ----------
// K=1024 fixed. 4 waves (2x2). LDS 64 KiB = 2 bufs x { Ah Al Bh Bl } each [128][32].
__global__ __launch_bounds__(256, 2) void k_gemm_mfma(
    const ushort_t* __restrict__ A_hi, const ushort_t* __restrict__ A_lo,
    const ushort_t* __restrict__ Bt_hi, const ushort_t* __restrict__ Bt_lo,
    ushort_t* __restrict__ C_hi, ushort_t* __restrict__ C_lo,
    float* __restrict__ Cf,
    int N)
{
    __shared__ ushort_t lds[32768];   // 2 x 16384

    const int tid  = threadIdx.x;
    const int wave = tid >> 6, lane = tid & 63;
    const int wr = wave >> 1, wc = wave & 1;
    const int fr = lane & 15, fq = lane >> 4;

    int nwg = gridDim.x * gridDim.y;
    int id = blockIdx.y * gridDim.x + blockIdx.x;
    if (!(nwg & 7)) { int cpx = nwg >> 3; id = (id & 7)*cpx + (id >> 3); }
    const int m0 = (id / gridDim.x) * 128, n0 = (id % gridDim.x) * 128;

    // staging coords: rows wave*32 + r*16 + (lane>>2); k-slot sq (same for r=0,1)
    const int sl = lane >> 2;
    const int sq = (lane & 3) ^ ((sl >> 1) & 3);   // (row>>1)&3 == ((lane>>2)>>1)&3 for both r
    const unsigned ga0 = (unsigned)(m0 + wave*32 + sl) * 1024u + (unsigned)sq * 8u;
    const unsigned gb0 = (unsigned)(n0 + wave*32 + sl) * 1024u + (unsigned)sq * 8u;
    const ushort_t* pa0 = A_hi  + ga0;       const ushort_t* pa1 = pa0 + 16384u;  // +16 rows
    const ushort_t* pal0 = A_lo + ga0;       const ushort_t* pal1 = pal0 + 16384u;
    const ushort_t* pb0 = Bt_hi + gb0;       const ushort_t* pb1 = pb0 + 16384u;
    const ushort_t* pbl0 = Bt_lo + gb0;      const ushort_t* pbl1 = pbl0 + 16384u;
    const unsigned sl0 = (unsigned)wave * 1024u;       // dest within region (r=0)
    const unsigned sl1 = sl0 + 512u;                   // r=1

    // fragment read base (per-lane; buf/region/i are immediates)
    const unsigned fb = (unsigned)fr*32u + (unsigned)((fq ^ ((fr >> 1) & 3)) * 8);
    const ushort_t* q0 = lds + fb;
    const ushort_t* q1 = q0 + 16384u;

    f32x4 acc[4][4] = {};

#define STG3(KT, WB) { \
    unsigned wb_ = (unsigned)(WB) * 16384u; \
    gload16(pa0  + (KT), lds + wb_ +           sl0); \
    gload16(pa1  + (KT), lds + wb_ +           sl1); \
    gload16(pal0 + (KT), lds + wb_ +  4096u +  sl0); \
    gload16(pal1 + (KT), lds + wb_ +  4096u +  sl1); \
    gload16(pb0  + (KT), lds + wb_ +  8192u +  sl0); \
    gload16(pb1  + (KT), lds + wb_ +  8192u +  sl1); \
    gload16(pbl0 + (KT), lds + wb_ + 12288u +  sl0); \
    gload16(pbl1 + (KT), lds + wb_ + 12288u +  sl1); \
}
#define RA3(P, hl, i) (*(const short8v*)((P) + (hl)*4096u + (unsigned)wr*2048u + (unsigned)(i)*512u))
#define RB3(P, hl, j) (*(const short8v*)((P) + 8192u + (hl)*4096u + (unsigned)wc*2048u + (unsigned)(j)*512u))
#define MM16(A8, B8, C4) __builtin_amdgcn_mfma_f32_16x16x32_bf16(A8, B8, C4, 0, 0, 0)

    STG3(0, 0);
    __syncthreads();

    #pragma unroll 1
    for (int kt = 0; kt < 1024; kt += 32) {
        const int par = (kt >> 5) & 1;
        const ushort_t* cp = par ? q1 : q0;

        short8v bh0 = RB3(cp,0,0), bl0 = RB3(cp,1,0);
        short8v bh1 = RB3(cp,0,1), bl1 = RB3(cp,1,1);
        short8v bh2 = RB3(cp,0,2), bl2 = RB3(cp,1,2);
        short8v bh3 = RB3(cp,0,3), bl3 = RB3(cp,1,3);

        if (kt + 32 < 1024) STG3(kt + 32, par ^ 1);

        __builtin_amdgcn_s_setprio(1);
        #pragma unroll
        for (int i = 0; i < 4; ++i) {
            short8v ah = RA3(cp,0,i), al = RA3(cp,1,i);
            acc[i][0] = MM16(ah, bh0, acc[i][0]);
            acc[i][1] = MM16(ah, bh1, acc[i][1]);
            acc[i][2] = MM16(ah, bh2, acc[i][2]);
            acc[i][3] = MM16(ah, bh3, acc[i][3]);
            acc[i][0] = MM16(ah, bl0, acc[i][0]);
            acc[i][1] = MM16(ah, bl1, acc[i][1]);
            acc[i][2] = MM16(ah, bl2, acc[i][2]);
            acc[i][3] = MM16(ah, bl3, acc[i][3]);
            acc[i][0] = MM16(al, bh0, acc[i][0]);
            acc[i][1] = MM16(al, bh1, acc[i][1]);
            acc[i][2] = MM16(al, bh2, acc[i][2]);
            acc[i][3] = MM16(al, bh3, acc[i][3]);
        }
        __builtin_amdgcn_s_setprio(0);

        __syncthreads();
    }

    #pragma unroll
    for (int i = 0; i < 4; ++i)
        #pragma unroll
        for (int j = 0; j < 4; ++j)
            #pragma unroll
            for (int r = 0; r < 4; ++r) {
                int row = m0 + wr*64 + i*16 + fq*4 + r;
                int col = n0 + wc*64 + j*16 + fr;
                float t = tanhf(acc[i][j][r]);
                size_t idx = (size_t)row*N + col;
                if (Cf) Cf[idx] = t;
                if (C_hi) {
                    ushort_t h = f2bf(t);
                    C_hi[idx] = h;
                    C_lo[idx] = f2bf(t - bf2f(h));
                }
            }
#undef STG3
#undef RA3
#undef RB3
#undef MM16
}

// ---------------- MFMA assignment + fused histogram ----------------
__global__ __launch_bounds__(256) void k_assign_mfma(
    const ushort_t* __restrict__ SEh, const ushort_t* __restrict__ SEl,
    const ushort_t* __restrict__ ch, const ushort_t* __restrict__ cl,
    const float* __restrict__ c2,
    int* __restrict__ sc, float* __restrict__ out_w,
    int* __restrict__ blockHist)
{
    __shared__ ushort_t lds[16384];
    __shared__ float c2s[512];
    __shared__ float redD[128][2];
    __shared__ int   redI[128][2];

    const int modal = blockIdx.y;
    const int t0 = blockIdx.x * 128;
    const int tid  = threadIdx.x;
    const int wave = tid >> 6, lane = tid & 63;
    const int wr = wave >> 1, wc = wave & 1;
    const int fr = lane & 15, fq = lane >> 4;

    const ushort_t* seh = SEh + (size_t)modal * NTOK * 256;
    const ushort_t* sel = SEl + (size_t)modal * NTOK * 256;

    c2s[tid] = c2[tid];
    c2s[tid + 256] = c2[tid + 256];

    int srow[2], sq[2], slbase[2];
    #pragma unroll
    for (int r = 0; r < 2; ++r) {
        int row = wave*32 + r*16 + (lane >> 2);
        srow[r]   = row;
        sq[r]     = (lane & 3) ^ ((row >> 1) & 3);
        slbase[r] = wave*1024 + r*512;
    }

    float bd[16]; int bi[16];
    #pragma unroll
    for (int s = 0; s < 16; ++s) { bd[s] = 3.4e38f; bi[s] = 0; }

    for (int j = 0; j < 4; ++j) {
        f32x4 acc[4][4] = {};
        for (int kt = 0; kt < 256; kt += 32) {
            __syncthreads();
            #pragma unroll
            for (int r = 0; r < 2; ++r) {
                size_t ga = (size_t)(t0 + srow[r]) * 256 + kt + sq[r]*8;
                size_t gc = (size_t)(j*128 + srow[r]) * 256 + kt + sq[r]*8;
                gload16(seh + ga, lds          + slbase[r]);
                gload16(sel + ga, lds + 4096   + slbase[r]);
                gload16(ch  + gc, lds + 8192   + slbase[r]);
                gload16(cl  + gc, lds + 12288  + slbase[r]);
            }
            __syncthreads();

            short8v ah[4], al[4], bh[4], bl[4];
            #pragma unroll
            for (int i = 0; i < 4; ++i) {
                int rowa = wr*64 + i*16 + fr;
                int offa = rowa*32 + ((fq ^ ((rowa >> 1) & 3)) * 8);
                ah[i] = *(const short8v*)(lds + offa);
                al[i] = *(const short8v*)(lds + 4096 + offa);
                int rowb = wc*64 + i*16 + fr;
                int offb = rowb*32 + ((fq ^ ((rowb >> 1) & 3)) * 8);
                bh[i] = *(const short8v*)(lds + 8192 + offb);
                bl[i] = *(const short8v*)(lds + 12288 + offb);
            }
            #pragma unroll
            for (int i = 0; i < 4; ++i)
                #pragma unroll
                for (int jj = 0; jj < 4; ++jj) {
                    acc[i][jj] = __builtin_amdgcn_mfma_f32_16x16x32_bf16(ah[i], bh[jj], acc[i][jj], 0, 0, 0);
                    acc[i][jj] = __builtin_amdgcn_mfma_f32_16x16x32_bf16(ah[i], bl[jj], acc[i][jj], 0, 0, 0);
                    acc[i][jj] = __builtin_amdgcn_mfma_f32_16x16x32_bf16(al[i], bh[jj], acc[i][jj], 0, 0, 0);
                }
        }
        #pragma unroll
        for (int i = 0; i < 4; ++i)
            #pragma unroll
            for (int jj = 0; jj < 4; ++jj) {
                int col = j*128 + wc*64 + jj*16 + fr;
                float cc = c2s[col];
                #pragma unroll
                for (int r = 0; r < 4; ++r) {
                    float d = cc - 2.f * acc[i][jj][r];
                    int s = i*4 + r;
                    if (d < bd[s]) { bd[s] = d; bi[s] = col; }
                }
            }
    }

    #pragma unroll
    for (int s = 0; s < 16; ++s) {
        #pragma unroll
        for (int off = 1; off < 16; off <<= 1) {
            float od = __shfl_xor(bd[s], off);
            int   oi = __shfl_xor(bi[s], off);
            if (od < bd[s] || (od == bd[s] && oi < bi[s])) { bd[s] = od; bi[s] = oi; }
        }
    }
    if (fr == 0) {
        #pragma unroll
        for (int i = 0; i < 4; ++i)
            #pragma unroll
            for (int r = 0; r < 4; ++r) {
                int tl = wr*64 + i*16 + fq*4 + r;
                redD[tl][wc] = bd[i*4 + r];
                redI[tl][wc] = bi[i*4 + r];
            }
    }
    __syncthreads();
    if (tid < 128) {
        float d0 = redD[tid][0], d1 = redD[tid][1];
        int   i0 = redI[tid][0], i1 = redI[tid][1];
        if (d1 < d0 || (d1 == d0 && i1 < i0)) { d0 = d1; i0 = i1; }
        int g = t0 + tid;
        sc[modal*NTOK + g] = i0;
        out_w[OFF_SC + (size_t)modal*NTOK + g] = (float)i0;
        atomicAdd(&blockHist[(modal*128 + (g >> 8))*512 + i0], 1);
    }
}

// ---------------- fp32 fallback assignment + fused histogram ----------------
__global__ __launch_bounds__(256) void k_assign(
    const float* __restrict__ out_ro,
    const float* __restrict__ c2,
    int* __restrict__ sc,
    float* __restrict__ out_w,
    int* __restrict__ blockHist)
{
    const int modal = blockIdx.y;
    const int tok0 = blockIdx.x * 64;
    const float* se   = out_ro + OFF_SE + (size_t)modal * NTOK * 256;
    const float* cent = out_ro + OFF_CENT;

    __shared__ float4 se4[64][64];
    __shared__ float4 ct4[64][64];

    const int tid = threadIdx.x;
    const int tt = tid & 15, cc = tid >> 4;

    {
        int rbase = tid >> 6;
        int d4 = tid & 63;
        #pragma unroll
        for (int i = 0; i < 16; ++i) {
            int t = i*4 + rbase;
            float4 v = *(const float4*)(se + (size_t)(tok0 + t)*256 + d4*4);
            se4[t][d4 ^ (t >> 2)] = v;
        }
    }
    __syncthreads();

    float e2r[4];
    #pragma unroll
    for (int k2 = 0; k2 < 4; ++k2) {
        float s = 0.f;
        for (int d4 = 0; d4 < 64; ++d4) {
            float4 v = se4[4*tt + k2][d4 ^ tt];
            s += dot4(v, v);
        }
        e2r[k2] = s;
    }

    float bd[4]; int bi[4];
    #pragma unroll
    for (int k2 = 0; k2 < 4; ++k2) { bd[k2] = 3.4e38f; bi[k2] = 0; }

    for (int ctile = 0; ctile < 8; ++ctile) {
        int c0 = ctile * 64;
        {
            int rbase = tid >> 6;
            int d4 = tid & 63;
            #pragma unroll
            for (int i = 0; i < 16; ++i) {
                int r = i*4 + rbase;
                float4 v = *(const float4*)(cent + (size_t)(c0 + r)*256 + d4*4);
                ct4[r][d4 ^ (r >> 2)] = v;
            }
        }
        __syncthreads();

        float accd[4][4];
        #pragma unroll
        for (int a = 0; a < 4; ++a)
            #pragma unroll
            for (int b = 0; b < 4; ++b) accd[a][b] = 0.f;

        for (int d4 = 0; d4 < 64; ++d4) {
            float4 sv[4], cv[4];
            #pragma unroll
            for (int k2 = 0; k2 < 4; ++k2) sv[k2] = se4[4*tt + k2][d4 ^ tt];
            #pragma unroll
            for (int jx = 0; jx < 4; ++jx) cv[jx] = ct4[4*cc + jx][d4 ^ cc];
            #pragma unroll
            for (int k2 = 0; k2 < 4; ++k2)
                #pragma unroll
                for (int jx = 0; jx < 4; ++jx)
                    accd[k2][jx] += dot4(sv[k2], cv[jx]);
        }

        #pragma unroll
        for (int jx = 0; jx < 4; ++jx) {
            int cidx = c0 + 4*cc + jx;
            float cj = c2[cidx];
            #pragma unroll
            for (int k2 = 0; k2 < 4; ++k2) {
                float d = cj + e2r[k2] - 2.f * accd[k2][jx];
                if (d < bd[k2]) { bd[k2] = d; bi[k2] = cidx; }
            }
        }
        __syncthreads();
    }

    float* red_d = (float*)ct4;
    int*   red_i = (int*)ct4 + 64*17;
    #pragma unroll
    for (int k2 = 0; k2 < 4; ++k2) {
        red_d[(4*tt + k2)*17 + cc] = bd[k2];
        red_i[(4*tt + k2)*17 + cc] = bi[k2];
    }
    __syncthreads();
    if (tid < 64) {
        float b = red_d[tid*17]; int ix = red_i[tid*17];
        #pragma unroll
        for (int q = 1; q < 16; ++q) {
            float d = red_d[tid*17 + q]; int i2 = red_i[tid*17 + q];
            if (d < b || (d == b && i2 < ix)) { b = d; ix = i2; }
        }
        int g = tok0 + tid;
        sc[modal*NTOK + g] = ix;
        out_w[OFF_SC + (size_t)modal*NTOK + g] = (float)ix;
        atomicAdd(&blockHist[(modal*128 + (g >> 8))*512 + ix], 1);
    }
}

// ---------------- per-class block scan + class exclusive scan ----------------
__global__ __launch_bounds__(512) void k_scan(const int* __restrict__ blockHist,
                                              int* __restrict__ blockBase,
                                              int* __restrict__ classBase,
                                              float* __restrict__ out)
{
    int modal = blockIdx.x;
    int c = threadIdx.x;
    int run = 0;
    for (int b = 0; b < 128; ++b) {
        int idx = (modal*128 + b)*512 + c;
        blockBase[idx] = run;
        run += blockHist[idx];
    }
    float* cnt = out + (modal ? OFF_CI : OFF_CT);
    cnt[c] = (float)run;

    __shared__ int s[512];
    s[c] = run;
    __syncthreads();
    int total = run;
    for (int off = 1; off < 512; off <<= 1) {
        int v = 0;
        if (c >= off) v = s[c - off];
        __syncthreads();
        s[c] += v;
        __syncthreads();
    }
    classBase[modal*512 + c] = s[c] - total;
}

__global__ __launch_bounds__(256) void k_scatter(const int* __restrict__ sc,
                                                 const int* __restrict__ blockBase,
                                                 const int* __restrict__ classBase,
                                                 float* __restrict__ out)
{
    int modal = blockIdx.y, blk = blockIdx.x, tid = threadIdx.x;
    __shared__ int cls[256];
    int t = blk*256 + tid;
    int c = sc[modal*NTOK + t];
    cls[tid] = c;
    __syncthreads();
    int rank = 0;
    for (int j = 0; j < tid; ++j) rank += (cls[j] == c) ? 1 : 0;
    int pos = classBase[modal*512 + c] + blockBase[(modal*128 + blk)*512 + c] + rank;
    float* oo = out + (modal ? OFF_OI : OFF_OT);
    oo[pos] = (float)t;
}

extern "C" void kernel_launch(void* const* d_in, const int* in_sizes, int n_in,
                              void* d_out, int out_size, void* d_ws, size_t ws_size,
                              hipStream_t stream)
{
    const float* text_emb  = (const float*)d_in[0];
    const float* image_emb = (const float*)d_in[1];
    const float* W[2][3] = {
        {(const float*)d_in[2], (const float*)d_in[3], (const float*)d_in[4]},
        {(const float*)d_in[5], (const float*)d_in[6], (const float*)d_in[7]}
    };
    const float* cent_raw = (const float*)d_in[8];
    float* out = (float*)d_out;
    char* w = (char*)d_ws;

    int*   sc        = (int*)w;
    int*   blockHist = (int*)(w + 0x40000);
    int*   blockBase = (int*)(w + 0xC0000);
    int*   classBase = (int*)(w + 0x140000);
    float* c2        = (float*)(w + 0x141000);
    ushort_t* cent_h = (ushort_t*)(w + 0x142000);
    ushort_t* cent_l = (ushort_t*)(w + 0x182000);

    ushort_t* wreg = (ushort_t*)(w + 0x200000);
    const size_t WM = 4*1048576 + 2*262144;

    ushort_t* SEh = (ushort_t*)(w + 0x1400000);
    ushort_t* SEl = (ushort_t*)(w + 0x3400000);

    bool mfmaAssign = true;
    size_t actoff = 0x5400000;
    int Mc = 0;
    for (int c = NTOK; c >= 256; c >>= 1)
        if (actoff + (size_t)c*8192 <= ws_size) { Mc = c; break; }
    if (Mc == 0) {
        mfmaAssign = false;
        actoff = 0x1400000;
        for (int c = NTOK; c >= 256; c >>= 1)
            if (actoff + (size_t)c*8192 <= ws_size) { Mc = c; break; }
        if (Mc == 0) Mc = 256;
    }
    ushort_t* act = (ushort_t*)(w + actoff);

    // zero the fused histogram (deterministic every call)
    hipMemsetAsync(blockHist, 0, 2*128*512*sizeof(int), stream);

    k_cent<<<dim3(512), dim3(64), 0, stream>>>(cent_raw, out, c2, cent_h, cent_l);
    k_prep<<<dim3(4672), dim3(256), 0, stream>>>(
        W[0][0], W[0][1], W[0][2], W[1][0], W[1][1], W[1][2], wreg, out);

    for (int m = 0; m < 2; ++m) {
        const float* emb = m ? image_emb : text_emb;
        ushort_t* w1h = wreg + (size_t)m*WM;
        ushort_t* w2h = w1h + 2*1048576;
        ushort_t* w3h = w1h + 4*1048576;
        ushort_t* w3l = w3h + 262144;

        ushort_t* Ah = act;
        ushort_t* Al = Ah + (size_t)Mc*1024;
        ushort_t* Hh = Al + (size_t)Mc*1024;
        ushort_t* Hl = Hh + (size_t)Mc*1024;

        for (int s0 = 0; s0 < NTOK; s0 += Mc) {
            k_gemm_l1<<<dim3((Mc/256)*4), dim3(512), 0, stream>>>(
                emb + (size_t)s0*1024, w1h, Hh, Hl, 1048576u, 1024);
            k_gemm_mfma256<<<dim3((Mc/256)*4), dim3(512), 0, stream>>>(
                Hh, w2h, Ah, Al, (unsigned)Mc*1024u, 1048576u, 1024);
            ushort_t* seh_ptr = mfmaAssign ? SEh + ((size_t)m*NTOK + s0)*256 : nullptr;
            ushort_t* sel_ptr = mfmaAssign ? SEl + ((size_t)m*NTOK + s0)*256 : nullptr;
            k_gemm_mfma<<<dim3(2, Mc/128), dim3(256), 0, stream>>>(
                Ah, Al, w3h, w3l, seh_ptr, sel_ptr,
                out + OFF_SE + ((size_t)m*NTOK + s0)*256, 256);
        }
    }

    if (mfmaAssign) {
        k_assign_mfma<<<dim3(256, 2), dim3(256), 0, stream>>>(
            SEh, SEl, cent_h, cent_l, c2, sc, out, blockHist);
    } else {
        k_assign<<<dim3(512, 2), dim3(256), 0, stream>>>(out, c2, sc, out, blockHist);
    }
    k_scan   <<<dim3(2),      dim3(512), 0, stream>>>(blockHist, blockBase, classBase, out);
    k_scatter<<<dim3(128, 2), dim3(256), 0, stream>>>(sc, blockBase, classBase, out);
}